// Round 4
// baseline (35.422 us; speedup 1.0000x reference)
//
#include <hip/hip_runtime.h>

#define KDIM 16
#define NSPIRAL 81

typedef float f4 __attribute__((ext_vector_type(4)));
typedef float f2 __attribute__((ext_vector_type(2)));

// spiral_pattern(4,4) flattened row-major (index c = y*9+x), values 1..81
__device__ __constant__ int d_spiral[NSPIRAL] = {
 74,73,72,71,70,69,68,67,66,
 75,44,43,42,41,40,39,38,65,
 76,45,22,21,20,19,18,37,64,
 77,46,23, 8, 7, 6,17,36,63,
 78,47,24, 9, 1, 5,16,35,62,
 79,48,25, 2, 3, 4,15,34,61,
 80,49,10,11,12,13,14,33,60,
 81,26,27,28,29,30,31,32,59,
 50,51,52,53,54,55,56,57,58
};

__device__ __forceinline__ f4 ntload4(const float* p) {
    return __builtin_nontemporal_load(reinterpret_cast<const f4*>(p));
}

struct Pix { f4 a[6]; f4 t; };

// ---- specialized fast path: C == 82 (rowlen 1312 floats = 328 f4) ----

__device__ __forceinline__ void load_pix82(const float* __restrict__ windows,
                                           const float* __restrict__ templates,
                                           int pix, int lane, Pix& P)
{
    const float* wrow = windows + (size_t)pix * 1312;
    P.t = ntload4(templates + (size_t)pix * KDIM + (lane & 3) * 4);
    #pragma unroll
    for (int it = 0; it < 5; ++it)
        P.a[it] = ntload4(wrow + (it * 64 + lane) * 4);
    P.a[5] = f4{0.f, 0.f, 0.f, 0.f};
    if (lane < 8) P.a[5] = ntload4(wrow + (320 + lane) * 4);
}

__device__ __forceinline__ void process_pix82(const Pix& P, const int* nb, int lane,
    int pix, int npix, const float* __restrict__ windows, float* __restrict__ out)
{
    int bk = 0x7FFFFFFF;
    int c81 = 0;
    #pragma unroll
    for (int it = 0; it < 6; ++it) {
        float s = fabsf(P.a[it].x - P.t.x) + fabsf(P.a[it].y - P.t.y)
                + fabsf(P.a[it].z - P.t.z) + fabsf(P.a[it].w - P.t.w);
        s += __shfl_xor(s, 1);
        s += __shfl_xor(s, 2);
        const int cost = (int)s;                 // exact integer <= 4080
        if (it < 5) {
            bk = min(bk, (cost << 14) | nb[it]);
        } else {
            if (lane < 4)        bk = min(bk, (cost << 14) | nb[5]);  // c=80
            if ((lane >> 2) == 1) c81 = cost;                          // c=81
        }
    }
    #pragma unroll
    for (int off = 32; off >= 1; off >>= 1)
        bk = min(bk, __shfl_xor(bk, off));
    c81 = __shfl(c81, 4);

    const int idx = bk & 127, mc = bk >> 14;
    const bool m  = c81 < mc;
    const int mi  = m ? NSPIRAL : idx;
    const int mcv = min(c81, mc);

    // output layout: [vec: npix*2][tmpl: npix*16][mask: npix][cost: npix]
    float* out_vec  = out;
    float* out_tmpl = out + (size_t)npix * 2;
    float* out_mask = out + (size_t)npix * 18;
    float* out_cost = out + (size_t)npix * 19;

    if (lane < 4) {
        const f4 w = *reinterpret_cast<const f4*>(
            windows + (size_t)pix * 1312 + mi * KDIM + lane * 4);
        __builtin_nontemporal_store(w,
            reinterpret_cast<f4*>(out_tmpl + (size_t)pix * KDIM + lane * 4));
    }
    if (lane == 0) {
        f2 v; v.x = (float)(4 - idx / 9); v.y = (float)(4 - idx % 9);
        __builtin_nontemporal_store(v, reinterpret_cast<f2*>(out_vec + (size_t)pix * 2));
        __builtin_nontemporal_store(m ? 1.0f : 0.0f, out_mask + pix);
        __builtin_nontemporal_store((float)mcv, out_cost + pix);
    }
}

__global__ __launch_bounds__(256, 4) void calc_vector82(
    const float* __restrict__ windows,
    const float* __restrict__ templates,
    float* __restrict__ out, int npix)
{
    const int lane = threadIdx.x & 63;
    const int gw = (int)((blockIdx.x * blockDim.x + threadIdx.x) >> 6);
    const int nw = (int)((gridDim.x * blockDim.x) >> 6);

    // per-lane packed key bases (spiral<<7 | c) for the 6 candidate slots
    int nb[6];
    #pragma unroll
    for (int it = 0; it < 6; ++it) {
        const int c = it * 16 + (lane >> 2);
        nb[it] = (c < NSPIRAL) ? ((d_spiral[c] << 7) | c) : 0;
    }

    int pix = gw;
    if (pix >= npix) return;
    Pix A, B;
    load_pix82(windows, templates, pix, lane, A);

    while (true) {
        int nxt = pix + nw;
        if (nxt < npix) load_pix82(windows, templates, nxt, lane, B);
        process_pix82(A, nb, lane, pix, npix, windows, out);
        pix = nxt;
        if (pix >= npix) return;

        nxt = pix + nw;
        if (nxt < npix) load_pix82(windows, templates, nxt, lane, A);
        process_pix82(B, nb, lane, pix, npix, windows, out);
        pix = nxt;
        if (pix >= npix) return;
    }
}

// ---- generic fallback (runtime C, one pixel per wave) ----

__global__ __launch_bounds__(256) void calc_vector_generic(
    const float* __restrict__ windows,
    const float* __restrict__ templates,
    float* __restrict__ out,
    int npix, int C)
{
    const int tid = threadIdx.x;
    const int wave = tid >> 6;
    const int lane = tid & 63;
    const int pix = blockIdx.x * 4 + wave;
    if (pix >= npix) return;

    const int rowlen = C * KDIM;
    const int nf4 = rowlen >> 2;
    const float* wrow = windows + (size_t)pix * rowlen;

    const int kseg = (lane & 3) * 4;
    const f4 t4 = ntload4(templates + (size_t)pix * KDIM + kseg);

    int bestkey = 0x7FFFFFFF;
    int cost81 = 0;

    #pragma unroll
    for (int it = 0; it < 6; ++it) {
        const int f = it * 64 + lane;
        const int c = it * 16 + (lane >> 2);
        float s = 0.0f;
        const bool act = f < nf4;
        if (act) {
            const f4 w4 = ntload4(wrow + f * 4);
            s = fabsf(w4.x - t4.x) + fabsf(w4.y - t4.y) +
                fabsf(w4.z - t4.z) + fabsf(w4.w - t4.w);
        }
        s += __shfl_xor(s, 1);
        s += __shfl_xor(s, 2);
        const int cost = (int)s;
        if (act && c < NSPIRAL) {
            const int key = (cost << 14) | (d_spiral[c] << 7) | c;
            bestkey = min(bestkey, key);
        }
        if (act && c == NSPIRAL) cost81 = cost;
    }

    #pragma unroll
    for (int off = 32; off >= 1; off >>= 1)
        bestkey = min(bestkey, __shfl_xor(bestkey, off));
    cost81 = __shfl(cost81, 4);

    const int idx = bestkey & 127, mc = bestkey >> 14;
    const bool hasmv = (C == NSPIRAL + 1);
    const bool m  = hasmv && (cost81 < mc);
    const int mi  = m ? NSPIRAL : idx;
    const int mcv = m ? cost81 : mc;

    float* out_vec  = out;
    float* out_tmpl = out + (size_t)npix * 2;
    float* out_mask = out + (size_t)npix * 18;
    float* out_cost = out + (size_t)npix * 19;

    if (lane < 4) {
        const f4 w = *reinterpret_cast<const f4*>(wrow + mi * KDIM + lane * 4);
        __builtin_nontemporal_store(w,
            reinterpret_cast<f4*>(out_tmpl + (size_t)pix * KDIM + lane * 4));
    }
    if (lane == 0) {
        f2 v; v.x = (float)(4 - idx / 9); v.y = (float)(4 - idx % 9);
        __builtin_nontemporal_store(v, reinterpret_cast<f2*>(out_vec + (size_t)pix * 2));
        __builtin_nontemporal_store(m ? 1.0f : 0.0f, out_mask + pix);
        __builtin_nontemporal_store((float)mcv, out_cost + pix);
    }
}

extern "C" void kernel_launch(void* const* d_in, const int* in_sizes, int n_in,
                              void* d_out, int out_size, void* d_ws, size_t ws_size,
                              hipStream_t stream) {
    const float* windows   = (const float*)d_in[0];
    const float* templates = (const float*)d_in[1];
    float* out = (float*)d_out;

    const int npix = in_sizes[1] / KDIM;          // B*H*W = 32400
    const int C    = in_sizes[0] / in_sizes[1];   // 82

    if (C == 82) {
        // persistent grid: ~4096 waves (1024 blocks), ~8 pixels per wave
        int blocks = (npix + 3) / 4;
        if (blocks > 1024) blocks = 1024;
        calc_vector82<<<blocks, 256, 0, stream>>>(windows, templates, out, npix);
    } else {
        const int blocks = (npix + 3) / 4;
        calc_vector_generic<<<blocks, 256, 0, stream>>>(windows, templates, out, npix, C);
    }
}

// Round 5
// 34.765 us; speedup vs baseline: 1.0189x; 1.0189x over previous
//
#include <hip/hip_runtime.h>

#define KDIM 16
#define NSPIRAL 81

typedef float f4 __attribute__((ext_vector_type(4)));
typedef float f2 __attribute__((ext_vector_type(2)));

// spiral_pattern(4,4) flattened row-major (index c = y*9+x), values 1..81
__device__ __constant__ int d_spiral[NSPIRAL] = {
 74,73,72,71,70,69,68,67,66,
 75,44,43,42,41,40,39,38,65,
 76,45,22,21,20,19,18,37,64,
 77,46,23, 8, 7, 6,17,36,63,
 78,47,24, 9, 1, 5,16,35,62,
 79,48,25, 2, 3, 4,15,34,61,
 80,49,10,11,12,13,14,33,60,
 81,26,27,28,29,30,31,32,59,
 50,51,52,53,54,55,56,57,58
};

__device__ __forceinline__ f4 ntload4(const float* p) {
    return __builtin_nontemporal_load(reinterpret_cast<const f4*>(p));
}

// C_CONST > 0: compile-time candidate count (guards fold). C_CONST < 0: runtime.
template<int C_CONST>
__global__ __launch_bounds__(256) void calc_vector_kernel(
    const float* __restrict__ windows,
    const float* __restrict__ templates,
    float* __restrict__ out,
    int npix, int C_rt)
{
    __shared__ int s_spiral[NSPIRAL];
    const int tid = threadIdx.x;
    if (tid < NSPIRAL) s_spiral[tid] = d_spiral[tid];
    __syncthreads();

    const int C    = (C_CONST > 0) ? C_CONST : C_rt;
    const int wave = tid >> 6;
    const int lane = tid & 63;
    const int pix = blockIdx.x * 4 + wave;
    if (pix >= npix) return;

    const int rowlen = C * KDIM;              // 1312 floats
    const int nf4 = rowlen >> 2;              // 328 float4s
    const float* wrow = windows + (size_t)pix * rowlen;

    // each lane owns k-segment (lane&3)*4 .. +3 of the template
    const int kseg = (lane & 3) * 4;
    const f4 t4 = ntload4(templates + (size_t)pix * KDIM + kseg);

    // load the full row into registers (compiler clusters these loads anyway,
    // so all 6 are simultaneously live even in the consume-immediately form)
    f4 a[6];
    #pragma unroll
    for (int it = 0; it < 6; ++it) {
        const int f = it * 64 + lane;
        const bool act = f < ((C_CONST > 0) ? (C_CONST * 4) : nf4);
        a[it] = f4{0.f, 0.f, 0.f, 0.f};
        if (act) a[it] = ntload4(wrow + f * 4);
    }

    int bestkey = 0x7FFFFFFF;
    int cost81 = 0;

    #pragma unroll
    for (int it = 0; it < 6; ++it) {
        const int f = it * 64 + lane;
        const int c = it * 16 + (lane >> 2);  // candidate this 4-lane group covers
        const bool act = f < ((C_CONST > 0) ? (C_CONST * 4) : nf4);
        float s = fabsf(a[it].x - t4.x) + fabsf(a[it].y - t4.y) +
                  fabsf(a[it].z - t4.z) + fabsf(a[it].w - t4.w);
        // sum the 4 lanes of the group -> full 16-wide SAD on every lane
        s += __shfl_xor(s, 1);
        s += __shfl_xor(s, 2);
        const int cost = (int)s;              // exact integer <= 4080
        if (act && c < NSPIRAL) {
            const int n = s_spiral[c];
            const int key = (cost << 14) | (n << 7) | c;
            bestkey = min(bestkey, key);
        }
        if (act && c == NSPIRAL) cost81 = cost;  // lanes 4..7 at it==5
    }

    // wave-wide min reduce of the packed key
    #pragma unroll
    for (int off = 32; off >= 1; off >>= 1)
        bestkey = min(bestkey, __shfl_xor(bestkey, off));
    cost81 = __shfl(cost81, 4);

    const int idx_bm      = bestkey & 127;
    const int min_cost_bm = bestkey >> 14;
    const bool mv_mask    = cost81 < min_cost_bm;
    const int min_idx     = mv_mask ? NSPIRAL : idx_bm;
    const int mcv         = min(cost81, min_cost_bm);

    // extract winning candidate's 16 floats from the saved registers (no
    // global refetch): owning iteration min_idx>>4 is wave-uniform;
    // source lane = (min_idx&15)*4 + (lane&3)
    f4 sel;
    switch (min_idx >> 4) {
        case 0:  sel = a[0]; break;
        case 1:  sel = a[1]; break;
        case 2:  sel = a[2]; break;
        case 3:  sel = a[3]; break;
        case 4:  sel = a[4]; break;
        default: sel = a[5]; break;
    }
    const int sl = (min_idx & 15) * 4 + (lane & 3);
    f4 win;
    win.x = __shfl(sel.x, sl);
    win.y = __shfl(sel.y, sl);
    win.z = __shfl(sel.z, sl);
    win.w = __shfl(sel.w, sl);

    // output layout: [vec: npix*2][tmpl: npix*16][mask: npix][cost: npix]
    float* out_vec  = out;
    float* out_tmpl = out + (size_t)npix * 2;
    float* out_mask = out + (size_t)npix * 18;
    float* out_cost = out + (size_t)npix * 19;

    if (lane < 4) {
        __builtin_nontemporal_store(win,
            reinterpret_cast<f4*>(out_tmpl + (size_t)pix * KDIM + lane * 4));
    }
    if (lane == 0) {
        f2 v; v.x = (float)(4 - idx_bm / 9); v.y = (float)(4 - idx_bm % 9);
        __builtin_nontemporal_store(v, reinterpret_cast<f2*>(out_vec + (size_t)pix * 2));
        __builtin_nontemporal_store(mv_mask ? 1.0f : 0.0f, out_mask + pix);
        __builtin_nontemporal_store((float)mcv, out_cost + pix);
    }
}

extern "C" void kernel_launch(void* const* d_in, const int* in_sizes, int n_in,
                              void* d_out, int out_size, void* d_ws, size_t ws_size,
                              hipStream_t stream) {
    const float* windows   = (const float*)d_in[0];
    const float* templates = (const float*)d_in[1];
    float* out = (float*)d_out;

    const int npix = in_sizes[1] / KDIM;          // B*H*W = 32400
    const int C    = in_sizes[0] / in_sizes[1];   // 82

    const int blocks = (npix + 3) / 4;            // 4 waves (pixels) per block
    if (C == 82) {
        calc_vector_kernel<82><<<blocks, 256, 0, stream>>>(windows, templates, out, npix, C);
    } else {
        calc_vector_kernel<-1><<<blocks, 256, 0, stream>>>(windows, templates, out, npix, C);
    }
}

// Round 6
// 32.931 us; speedup vs baseline: 1.0756x; 1.0557x over previous
//
#include <hip/hip_runtime.h>

#define KDIM 16
#define NSPIRAL 81

typedef float f4 __attribute__((ext_vector_type(4)));
typedef float f2 __attribute__((ext_vector_type(2)));

// Packed tie-break key bases: (spiral_n << 7) | c for candidate c (c = y*9+x),
// entries 81..95 are padding (guarded out). spiral_n from spiral_pattern(4,4).
__device__ __constant__ int d_nb[96] = {
 (74<<7)|0,(73<<7)|1,(72<<7)|2,(71<<7)|3,(70<<7)|4,(69<<7)|5,(68<<7)|6,(67<<7)|7,(66<<7)|8,
 (75<<7)|9,(44<<7)|10,(43<<7)|11,(42<<7)|12,(41<<7)|13,(40<<7)|14,(39<<7)|15,(38<<7)|16,(65<<7)|17,
 (76<<7)|18,(45<<7)|19,(22<<7)|20,(21<<7)|21,(20<<7)|22,(19<<7)|23,(18<<7)|24,(37<<7)|25,(64<<7)|26,
 (77<<7)|27,(46<<7)|28,(23<<7)|29,( 8<<7)|30,( 7<<7)|31,( 6<<7)|32,(17<<7)|33,(36<<7)|34,(63<<7)|35,
 (78<<7)|36,(47<<7)|37,(24<<7)|38,( 9<<7)|39,( 1<<7)|40,( 5<<7)|41,(16<<7)|42,(35<<7)|43,(62<<7)|44,
 (79<<7)|45,(48<<7)|46,(25<<7)|47,( 2<<7)|48,( 3<<7)|49,( 4<<7)|50,(15<<7)|51,(34<<7)|52,(61<<7)|53,
 (80<<7)|54,(49<<7)|55,(10<<7)|56,(11<<7)|57,(12<<7)|58,(13<<7)|59,(14<<7)|60,(33<<7)|61,(60<<7)|62,
 (81<<7)|63,(26<<7)|64,(27<<7)|65,(28<<7)|66,(29<<7)|67,(30<<7)|68,(31<<7)|69,(32<<7)|70,(59<<7)|71,
 (50<<7)|72,(51<<7)|73,(52<<7)|74,(53<<7)|75,(54<<7)|76,(55<<7)|77,(56<<7)|78,(57<<7)|79,(58<<7)|80,
 0,0,0,0,0,0,0,0,0,0,0,0,0,0,0
};

__device__ __forceinline__ f4 ntload4(const float* p) {
    return __builtin_nontemporal_load(reinterpret_cast<const f4*>(p));
}

// C_CONST > 0: compile-time candidate count (guards fold). C_CONST < 0: runtime.
template<int C_CONST>
__global__ __launch_bounds__(256) void calc_vector_kernel(
    const float* __restrict__ windows,
    const float* __restrict__ templates,
    float* __restrict__ out,
    int npix, int C_rt)
{
    const int tid = threadIdx.x;
    const int C    = (C_CONST > 0) ? C_CONST : C_rt;
    const int wave = tid >> 6;
    const int lane = tid & 63;
    const int pix = blockIdx.x * 4 + wave;
    if (pix >= npix) return;

    const int rowlen = C * KDIM;              // 1312 floats
    const int nf4 = rowlen >> 2;              // 328 float4s
    const float* wrow = windows + (size_t)pix * rowlen;

    // each lane owns k-segment (lane&3)*4 .. +3 of the template
    const int kseg = (lane & 3) * 4;
    const f4 t4 = ntload4(templates + (size_t)pix * KDIM + kseg);

    const int g = lane >> 2;                  // 4-lane group id (candidate slot)

    int bestkey = 0x7FFFFFFF;
    int cost81 = 0;

    #pragma unroll
    for (int it = 0; it < 6; ++it) {
        const int f = it * 64 + lane;         // float4 index within row
        const int c = it * 16 + g;            // candidate this 4-lane group covers
        const bool act = f < ((C_CONST > 0) ? (C_CONST * 4) : nf4);
        float s = 0.0f;
        if (act) {
            const f4 w4 = ntload4(wrow + f * 4);
            s = fabsf(w4.x - t4.x) + fabsf(w4.y - t4.y) +
                fabsf(w4.z - t4.z) + fabsf(w4.w - t4.w);
        }
        // sum the 4 lanes of the group -> full 16-wide SAD on every lane
        s += __shfl_xor(s, 1);
        s += __shfl_xor(s, 2);
        const int cost = (int)s;              // exact integer <= 4080
        if (act && c < NSPIRAL) {
            const int key = (cost << 14) | d_nb[c];
            bestkey = min(bestkey, key);
        }
        if (act && c == NSPIRAL) cost81 = cost;  // lanes 4..7 at it==5
    }

    // wave-wide min reduce of the packed key
    #pragma unroll
    for (int off = 32; off >= 1; off >>= 1)
        bestkey = min(bestkey, __shfl_xor(bestkey, off));
    cost81 = __shfl(cost81, 4);

    const int idx_bm      = bestkey & 127;
    const int min_cost_bm = bestkey >> 14;
    const bool mv_mask    = cost81 < min_cost_bm;
    const int min_idx     = mv_mask ? NSPIRAL : idx_bm;
    const int mcv         = min(cost81, min_cost_bm);

    // output layout: [vec: npix*2][tmpl: npix*16][mask: npix][cost: npix]
    float* out_vec  = out;
    float* out_tmpl = out + (size_t)npix * 2;
    float* out_mask = out + (size_t)npix * 18;
    float* out_cost = out + (size_t)npix * 19;

    if (lane < 4) {
        const f4 w = *reinterpret_cast<const f4*>(wrow + min_idx * KDIM + lane * 4);
        __builtin_nontemporal_store(w,
            reinterpret_cast<f4*>(out_tmpl + (size_t)pix * KDIM + lane * 4));
    }
    if (lane == 0) {
        f2 v; v.x = (float)(4 - idx_bm / 9); v.y = (float)(4 - idx_bm % 9);
        __builtin_nontemporal_store(v, reinterpret_cast<f2*>(out_vec + (size_t)pix * 2));
        __builtin_nontemporal_store(mv_mask ? 1.0f : 0.0f, out_mask + pix);
        __builtin_nontemporal_store((float)mcv, out_cost + pix);
    }
}

extern "C" void kernel_launch(void* const* d_in, const int* in_sizes, int n_in,
                              void* d_out, int out_size, void* d_ws, size_t ws_size,
                              hipStream_t stream) {
    const float* windows   = (const float*)d_in[0];
    const float* templates = (const float*)d_in[1];
    float* out = (float*)d_out;

    const int npix = in_sizes[1] / KDIM;          // B*H*W = 32400
    const int C    = in_sizes[0] / in_sizes[1];   // 82

    const int blocks = (npix + 3) / 4;            // 4 waves (pixels) per block
    if (C == 82) {
        calc_vector_kernel<82><<<blocks, 256, 0, stream>>>(windows, templates, out, npix, C);
    } else {
        calc_vector_kernel<-1><<<blocks, 256, 0, stream>>>(windows, templates, out, npix, C);
    }
}